// Round 10
// baseline (240.163 us; speedup 1.0000x reference)
//
#include <hip/hip_runtime.h>

typedef short short8 __attribute__((ext_vector_type(8)));
typedef float f32x4 __attribute__((ext_vector_type(4)));

#define N_NODES 100000
#define N_A     50000
#define N_EDGES 500000
#define N_T     4
#define D_IN    128
#define HF      128
#define BCOLS   144                  // 128 ft cols + 4 el + 4 er + 8 zero pad
#define TN      (N_T * N_NODES)
#define TE      (N_T * N_EDGES)
#define NB1     ((TN + 1023) / 1024) // 391 scan blocks
#define TILE_E  (BCOLS * D_IN)       // 18432 elems = 36864 B per (t) B-tile
#define LOG2E   1.44269504088896340736f
#define PAIRS   (2 * N_NODES)        // (node, slot) pairs
#define NPBLK   ((PAIRS + 255) / 256)

__device__ __forceinline__ unsigned short f2b(float f) {
  unsigned int u = __float_as_uint(f);
  u += 0x7FFFu + ((u >> 16) & 1u);
  return (unsigned short)(u >> 16);
}
__device__ __forceinline__ unsigned int pk2(float lo, float hi) {
  return (unsigned int)f2b(lo) | ((unsigned int)f2b(hi) << 16);
}
__device__ __forceinline__ float blo(unsigned int u) { return __uint_as_float(u << 16); }
__device__ __forceinline__ float bhi(unsigned int u) { return __uint_as_float(u & 0xFFFF0000u); }

// K0: fused prep. Blocks 0-1: Bt[t][144][128] bf16, XOR-swizzled
// ((j*128+k) ^ ((j&7)<<3)); rows 128..135 hold W@attn_{l,r} PRE-SCALED by
// log2(e) so gather can use exp2. Blocks 2-33: WmT (permuted-k merge weights).
__global__ __launch_bounds__(256) void k_prep(const float* __restrict__ W,
    const float* __restrict__ al, const float* __restrict__ ar,
    const float* __restrict__ Wm,
    unsigned short* __restrict__ Bt, unsigned short* __restrict__ WmT)
{
  if (blockIdx.x < 2) {
    int idx = blockIdx.x * 256 + threadIdx.x;
    int t = idx >> 7, k = idx & 127;
    const float* Wr = W + ((size_t)t * D_IN + k) * HF;
    unsigned short* o = Bt + (size_t)t * TILE_E;
    for (int j = 0; j < HF; ++j)
      o[(j * D_IN + k) ^ ((j & 7) << 3)] = f2b(Wr[j]);
    for (int h = 0; h < 4; ++h) {
      float sl = 0.f, sr = 0.f;
      const float* alh = al + (t * 4 + h) * 32;
      const float* arh = ar + (t * 4 + h) * 32;
      for (int f = 0; f < 32; ++f) { float w = Wr[h * 32 + f]; sl += w * alh[f]; sr += w * arh[f]; }
      int jl = 128 + h, jr = 132 + h;
      o[(jl * D_IN + k) ^ ((jl & 7) << 3)] = f2b(sl * LOG2E);
      o[(jr * D_IN + k) ^ ((jr & 7) << 3)] = f2b(sr * LOG2E);
    }
    for (int j = 136; j < 144; ++j)
      o[(j * D_IN + k) ^ ((j & 7) << 3)] = 0;
  } else {
    int idx = (blockIdx.x - 2) * 256 + threadIdx.x;
    int kidx = idx >> 5, j = idx & 31;
    int slot = kidx >> 7, p = kidx & 127;
    int col = (p & 7) * 16 + (p >> 3);
    WmT[j * 256 + kidx] = f2b(Wm[(slot * 128 + col) * 32 + j]);
  }
}

// K1: projection GEMM (proven shape). Block = 64 rows (4 waves x 16),
// grid 1563, launch_bounds(256,4) -> ~52 VGPR, no spill, 4 blocks/CU.
__global__ __launch_bounds__(256, 4) void k_proj(const float* __restrict__ feat,
    const unsigned short* __restrict__ Btg,
    unsigned short* __restrict__ ftg,
    float* __restrict__ elg, float* __restrict__ erg)
{
  __shared__ __align__(16) unsigned short Bs[TILE_E];      // 36.8 KB -> 4 blocks/CU
  const int tid = threadIdx.x;
  const int wave = tid >> 6, lane = tid & 63;
  const int l15 = lane & 15, g = lane >> 4;
  const int wrow0 = blockIdx.x * 64 + wave * 16;

  short8 a[4];
  {
    int row = wrow0 + l15;
    const float* fr = feat + (size_t)(row < N_NODES ? row : N_NODES - 1) * D_IN;
#pragma unroll
    for (int kt = 0; kt < 4; ++kt) {
      float4 v0 = *(const float4*)(fr + kt * 32 + g * 8);
      float4 v1 = *(const float4*)(fr + kt * 32 + g * 8 + 4);
      short8 s;
      s[0] = (short)f2b(v0.x); s[1] = (short)f2b(v0.y);
      s[2] = (short)f2b(v0.z); s[3] = (short)f2b(v0.w);
      s[4] = (short)f2b(v1.x); s[5] = (short)f2b(v1.y);
      s[6] = (short)f2b(v1.z); s[7] = (short)f2b(v1.w);
      a[kt] = s;
    }
  }

  for (int t = 0; t < N_T; ++t) {
    if (t > 0) __syncthreads();
    {
      const uint4* src = (const uint4*)(Btg + (size_t)t * TILE_E);
      uint4* dstv = (uint4*)Bs;
#pragma unroll
      for (int i = 0; i < 9; ++i)
        dstv[i * 256 + tid] = src[i * 256 + tid];
    }
    __syncthreads();

    f32x4 acc[8];
#pragma unroll
    for (int ct = 0; ct < 8; ++ct) {
      f32x4 c = {0.f, 0.f, 0.f, 0.f};
#pragma unroll
      for (int kt = 0; kt < 4; ++kt) {
        int row = ct * 16 + l15;
        int boff = (row * 256 + kt * 64 + g * 16) ^ ((l15 & 7) << 4);
        short8 b = *(const short8*)((const char*)Bs + boff);
        c = __builtin_amdgcn_mfma_f32_16x16x32_bf16(a[kt], b, c, 0, 0, 0);
      }
      acc[ct] = c;
    }
    {
      f32x4 c8 = {0.f, 0.f, 0.f, 0.f};
#pragma unroll
      for (int kt = 0; kt < 4; ++kt) {
        int row = 128 + l15;
        int boff = (row * 256 + kt * 64 + g * 16) ^ ((l15 & 7) << 4);
        short8 b = *(const short8*)((const char*)Bs + boff);
        c8 = __builtin_amdgcn_mfma_f32_16x16x32_bf16(a[kt], b, c8, 0, 0, 0);
      }
      if (l15 < 8) {
#pragma unroll
        for (int r = 0; r < 4; ++r) {
          int row = wrow0 + g * 4 + r;
          if (row < N_NODES) {
            float v = c8[r];
            if (l15 < 4) elg[((size_t)t * N_NODES + row) * 4 + l15] = v;
            else         erg[((size_t)t * N_NODES + row) * 4 + (l15 - 4)] = v;
          }
        }
      }
    }
#pragma unroll
    for (int r = 0; r < 4; ++r) {
      int row = wrow0 + g * 4 + r;
      if (row < N_NODES) {
        uint4 o;
        o.x = pk2(acc[0][r], acc[1][r]);
        o.y = pk2(acc[2][r], acc[3][r]);
        o.z = pk2(acc[4][r], acc[5][r]);
        o.w = pk2(acc[6][r], acc[7][r]);
        *(uint4*)(ftg + ((size_t)t * N_NODES + row) * HF + l15 * 8) = o;
      }
    }
  }
}

// K2: histogram of kept edges by (t,dst) + per-edge within-bucket rank
__global__ __launch_bounds__(256) void k_hist(const int* __restrict__ dst,
    int* __restrict__ cnt, int* __restrict__ rank) {
  int idx = blockIdx.x * 256 + threadIdx.x;
  if (idx >= TE) return;
  int t = idx / N_EDGES;
  int d = dst[idx];
  bool keep = (t < 2) ? (d < N_A) : (d >= N_A);
  if (keep) rank[idx] = atomicAdd(&cnt[t * N_NODES + d], 1);
}

__global__ __launch_bounds__(256) void k_scan1(const int* __restrict__ cnt,
    int* __restrict__ ofs, int* __restrict__ bsum) {
  __shared__ int ts[256];
  int b = blockIdx.x, t = threadIdx.x;
  int base = b * 1024 + t * 4;
  int v0 = 0, v1 = 0, v2 = 0, v3 = 0;
  if (base + 0 < TN) v0 = cnt[base + 0];
  if (base + 1 < TN) v1 = cnt[base + 1];
  if (base + 2 < TN) v2 = cnt[base + 2];
  if (base + 3 < TN) v3 = cnt[base + 3];
  int s = v0 + v1 + v2 + v3;
  ts[t] = s;
  __syncthreads();
  for (int o = 1; o < 256; o <<= 1) {
    int x = (t >= o) ? ts[t - o] : 0;
    __syncthreads();
    ts[t] += x;
    __syncthreads();
  }
  int run = ts[t] - s;
  if (base + 0 < TN) ofs[base + 0] = run; run += v0;
  if (base + 1 < TN) ofs[base + 1] = run; run += v1;
  if (base + 2 < TN) ofs[base + 2] = run; run += v2;
  if (base + 3 < TN) ofs[base + 3] = run;
  if (t == 255) bsum[b] = ts[255];
}

__global__ __launch_bounds__(512) void k_scan2(int* __restrict__ bsum) {
  __shared__ int ts[512];
  int t = threadIdx.x;
  int v = (t < NB1) ? bsum[t] : 0;
  ts[t] = v;
  __syncthreads();
  for (int o = 1; o < 512; o <<= 1) {
    int x = (t >= o) ? ts[t - o] : 0;
    __syncthreads();
    ts[t] += x;
    __syncthreads();
  }
  if (t < NB1) bsum[t] = ts[t] - v;
}

// K3: slim scatter: 4 B record = src ft-row index; position from ofs+bsum+rank.
__global__ __launch_bounds__(256) void k_scatter(const int* __restrict__ src, const int* __restrict__ dst,
    const int* __restrict__ ofs, const int* __restrict__ bsum, const int* __restrict__ rank,
    int* __restrict__ bkt) {
  int idx = blockIdx.x * 256 + threadIdx.x;
  if (idx >= TE) return;
  int t = idx / N_EDGES;
  int d = dst[idx];
  bool keep = (t < 2) ? (d < N_A) : (d >= N_A);
  if (!keep) return;
  int key = t * N_NODES + d;
  int p = ofs[key] + bsum[key >> 10] + rank[idx];
  bkt[p] = t * N_NODES + src[idx];
}

// Degree sort of (node,slot) pairs: 64 bins (degree clamped to 63).
// K_d1: global degree histogram (block-local LDS first).
__global__ __launch_bounds__(256) void k_d1(const int* __restrict__ cnt, int* __restrict__ gdh) {
  __shared__ int lh[64];
  int tid = threadIdx.x;
  if (tid < 64) lh[tid] = 0;
  __syncthreads();
  int pid = blockIdx.x * 256 + tid;
  if (pid < PAIRS) {
    int n = pid >> 1, slot = pid & 1;
    int t = slot + ((n >= N_A) ? 2 : 0);
    int c = cnt[t * N_NODES + n];
    atomicAdd(&lh[c < 63 ? c : 63], 1);
  }
  __syncthreads();
  if (tid < 64 && lh[tid]) atomicAdd(&gdh[tid], lh[tid]);
}

// K_d2: exclusive scan of the 64 bins.
__global__ __launch_bounds__(64) void k_d2(const int* __restrict__ gdh, int* __restrict__ dbase) {
  __shared__ int ts[64];
  int t = threadIdx.x;
  int v = gdh[t];
  ts[t] = v;
  __syncthreads();
  for (int o = 1; o < 64; o <<= 1) {
    int x = (t >= o) ? ts[t - o] : 0;
    __syncthreads();
    ts[t] += x;
    __syncthreads();
  }
  dbase[t] = ts[t] - v;
}

// K_d3: ranked placement -> order[] lists pair ids sorted by degree.
__global__ __launch_bounds__(256) void k_d3(const int* __restrict__ cnt,
    const int* __restrict__ dbase, int* __restrict__ dcur, int* __restrict__ order) {
  __shared__ int lh[64];
  __shared__ int lbase[64];
  int tid = threadIdx.x;
  if (tid < 64) lh[tid] = 0;
  __syncthreads();
  int pid = blockIdx.x * 256 + tid;
  int bin = 0, lr = 0;
  bool ok = pid < PAIRS;
  if (ok) {
    int n = pid >> 1, slot = pid & 1;
    int t = slot + ((n >= N_A) ? 2 : 0);
    int c = cnt[t * N_NODES + n];
    bin = c < 63 ? c : 63;
    lr = atomicAdd(&lh[bin], 1);
  }
  __syncthreads();
  if (tid < 64) lbase[tid] = lh[tid] ? atomicAdd(&dcur[tid], lh[tid]) : 0;
  __syncthreads();
  if (ok) order[dbase[bin] + lbase[bin] + lr] = pid;
}

// K4: gather. 8 pairs per wave taken CONSECUTIVELY from the degree-sorted
// order (groups in a wave have ~equal degree -> minimal exec-mask waste).
// 8 lanes per pair. Per edge: 4 B record + 16 B el (broadcast) + 2x16 B ft;
// w[h] = exp2(fmax(s, 0.2s)), s pre-scaled by log2e. 2x unrolled.
__global__ __launch_bounds__(256) void k_gather(const int* __restrict__ order,
    const int* __restrict__ bkt,
    const int* __restrict__ ofs, const int* __restrict__ cnt, const int* __restrict__ bsum,
    const float* __restrict__ elg, const float* __restrict__ erg,
    const uint4* __restrict__ ftu, uint4* __restrict__ aggb)
{
  int wid = blockIdx.x * 4 + (threadIdx.x >> 6);
  int lane = threadIdx.x & 63;
  int g8 = lane >> 3, l7 = lane & 7;
  int pid = order[wid * 8 + g8];               // degree-sorted pair id
  int n = pid >> 1, slot = pid & 1;
  int t = slot + ((n >= N_A) ? 2 : 0);
  int key = t * N_NODES + n;
  int base = ofs[key] + bsum[key >> 10];
  int c = cnt[key];
  float4 er4 = *(const float4*)(erg + (size_t)key * 4);
  float a00 = 0.f, a01 = 0.f, a02 = 0.f, a03 = 0.f, a04 = 0.f, a05 = 0.f, a06 = 0.f, a07 = 0.f;
  float a10 = 0.f, a11 = 0.f, a12 = 0.f, a13 = 0.f, a14 = 0.f, a15 = 0.f, a16 = 0.f, a17 = 0.f;
  float d0 = 0.f, d1 = 0.f, d2 = 0.f, d3 = 0.f;
  int qb = l7 * 2;
  int i = 0;
  for (; i + 1 < c; i += 2) {
    int s0 = bkt[base + i];
    int s1 = bkt[base + i + 1];
    float4 el0 = *(const float4*)(elg + (size_t)s0 * 4);
    float4 el1 = *(const float4*)(elg + (size_t)s1 * 4);
    uint4 u0a = ftu[(size_t)s0 * 16 + qb];
    uint4 u0b = ftu[(size_t)s0 * 16 + qb + 1];
    uint4 u1a = ftu[(size_t)s1 * 16 + qb];
    uint4 u1b = ftu[(size_t)s1 * 16 + qb + 1];
    float s, w0, w1, w2, w3;
    s = el0.x + er4.x; w0 = exp2f(fmaxf(s, 0.2f * s));
    s = el0.y + er4.y; w1 = exp2f(fmaxf(s, 0.2f * s));
    s = el0.z + er4.z; w2 = exp2f(fmaxf(s, 0.2f * s));
    s = el0.w + er4.w; w3 = exp2f(fmaxf(s, 0.2f * s));
    d0 += w0; d1 += w1; d2 += w2; d3 += w3;
    a00 += w0 * blo(u0a.x); a01 += w0 * bhi(u0a.x);
    a02 += w1 * blo(u0a.y); a03 += w1 * bhi(u0a.y);
    a04 += w2 * blo(u0a.z); a05 += w2 * bhi(u0a.z);
    a06 += w3 * blo(u0a.w); a07 += w3 * bhi(u0a.w);
    a10 += w0 * blo(u0b.x); a11 += w0 * bhi(u0b.x);
    a12 += w1 * blo(u0b.y); a13 += w1 * bhi(u0b.y);
    a14 += w2 * blo(u0b.z); a15 += w2 * bhi(u0b.z);
    a16 += w3 * blo(u0b.w); a17 += w3 * bhi(u0b.w);
    s = el1.x + er4.x; w0 = exp2f(fmaxf(s, 0.2f * s));
    s = el1.y + er4.y; w1 = exp2f(fmaxf(s, 0.2f * s));
    s = el1.z + er4.z; w2 = exp2f(fmaxf(s, 0.2f * s));
    s = el1.w + er4.w; w3 = exp2f(fmaxf(s, 0.2f * s));
    d0 += w0; d1 += w1; d2 += w2; d3 += w3;
    a00 += w0 * blo(u1a.x); a01 += w0 * bhi(u1a.x);
    a02 += w1 * blo(u1a.y); a03 += w1 * bhi(u1a.y);
    a04 += w2 * blo(u1a.z); a05 += w2 * bhi(u1a.z);
    a06 += w3 * blo(u1a.w); a07 += w3 * bhi(u1a.w);
    a10 += w0 * blo(u1b.x); a11 += w0 * bhi(u1b.x);
    a12 += w1 * blo(u1b.y); a13 += w1 * bhi(u1b.y);
    a14 += w2 * blo(u1b.z); a15 += w2 * bhi(u1b.z);
    a16 += w3 * blo(u1b.w); a17 += w3 * bhi(u1b.w);
  }
  if (i < c) {
    int s0 = bkt[base + i];
    float4 el0 = *(const float4*)(elg + (size_t)s0 * 4);
    uint4 u0a = ftu[(size_t)s0 * 16 + qb];
    uint4 u0b = ftu[(size_t)s0 * 16 + qb + 1];
    float s, w0, w1, w2, w3;
    s = el0.x + er4.x; w0 = exp2f(fmaxf(s, 0.2f * s));
    s = el0.y + er4.y; w1 = exp2f(fmaxf(s, 0.2f * s));
    s = el0.z + er4.z; w2 = exp2f(fmaxf(s, 0.2f * s));
    s = el0.w + er4.w; w3 = exp2f(fmaxf(s, 0.2f * s));
    d0 += w0; d1 += w1; d2 += w2; d3 += w3;
    a00 += w0 * blo(u0a.x); a01 += w0 * bhi(u0a.x);
    a02 += w1 * blo(u0a.y); a03 += w1 * bhi(u0a.y);
    a04 += w2 * blo(u0a.z); a05 += w2 * bhi(u0a.z);
    a06 += w3 * blo(u0a.w); a07 += w3 * bhi(u0a.w);
    a10 += w0 * blo(u0b.x); a11 += w0 * bhi(u0b.x);
    a12 += w1 * blo(u0b.y); a13 += w1 * bhi(u0b.y);
    a14 += w2 * blo(u0b.z); a15 += w2 * bhi(u0b.z);
    a16 += w3 * blo(u0b.w); a17 += w3 * bhi(u0b.w);
  }
  float i0 = (c > 0) ? 1.f / d0 : 0.f;
  float i1 = (c > 0) ? 1.f / d1 : 0.f;
  float i2 = (c > 0) ? 1.f / d2 : 0.f;
  float i3 = (c > 0) ? 1.f / d3 : 0.f;
  uint4 oA, oB;
  oA.x = pk2(a00 * i0, a01 * i0);
  oA.y = pk2(a02 * i1, a03 * i1);
  oA.z = pk2(a04 * i2, a05 * i2);
  oA.w = pk2(a06 * i3, a07 * i3);
  oB.x = pk2(a10 * i0, a11 * i0);
  oB.y = pk2(a12 * i1, a13 * i1);
  oB.z = pk2(a14 * i2, a15 * i2);
  oB.w = pk2(a16 * i3, a17 * i3);
  size_t ob = (size_t)n * 32 + slot * 16 + qb;
  aggb[ob] = oA;
  aggb[ob + 1] = oB;
}

// K5: merge GEMM via MFMA. 64 nodes/block, out = agg(bf16, permuted-k) @ WmT + bm.
__global__ __launch_bounds__(256) void k_merge(const unsigned short* __restrict__ aggb,
    const unsigned short* __restrict__ WmT, const float* __restrict__ bm,
    float* __restrict__ out)
{
  __shared__ __align__(16) unsigned short Al[64 * 264];
  __shared__ __align__(16) unsigned short Bl[32 * 264];
  int n0 = blockIdx.x * 64;
  int tid = threadIdx.x;
  const uint4* asrc = (const uint4*)(aggb + (size_t)n0 * 256);
  for (int i = tid; i < 2048; i += 256) {
    int r = i >> 5, c = i & 31;
    *(uint4*)&Al[r * 264 + c * 8] = asrc[r * 32 + c];
  }
  for (int i = tid; i < 1024; i += 256) {
    int r = i >> 5, c = i & 31;
    *(uint4*)&Bl[r * 264 + c * 8] = ((const uint4*)WmT)[r * 32 + c];
  }
  __syncthreads();
  int wave = tid >> 6, lane = tid & 63;
  int l15 = lane & 15, lk = (lane >> 4) * 8;
  short8 a[8];
#pragma unroll
  for (int kt = 0; kt < 8; ++kt)
    a[kt] = *(const short8*)&Al[(wave * 16 + l15) * 264 + kt * 32 + lk];
  f32x4 acc0 = {0.f, 0.f, 0.f, 0.f}, acc1 = {0.f, 0.f, 0.f, 0.f};
#pragma unroll
  for (int kt = 0; kt < 8; ++kt) {
    short8 b0 = *(const short8*)&Bl[l15 * 264 + kt * 32 + lk];
    short8 b1 = *(const short8*)&Bl[(16 + l15) * 264 + kt * 32 + lk];
    acc0 = __builtin_amdgcn_mfma_f32_16x16x32_bf16(a[kt], b0, acc0, 0, 0, 0);
    acc1 = __builtin_amdgcn_mfma_f32_16x16x32_bf16(a[kt], b1, acc1, 0, 0, 0);
  }
  float bm0 = bm[l15], bm1 = bm[16 + l15];
#pragma unroll
  for (int r = 0; r < 4; ++r) {
    int row = n0 + wave * 16 + (lane >> 4) * 4 + r;
    if (row < N_NODES) {
      out[(size_t)row * 32 + l15] = acc0[r] + bm0;
      out[(size_t)row * 32 + 16 + l15] = acc1[r] + bm1;
    }
  }
}

extern "C" void kernel_launch(void* const* d_in, const int* in_sizes, int n_in,
                              void* d_out, int out_size, void* d_ws, size_t ws_size,
                              hipStream_t stream)
{
  const float* feat = (const float*)d_in[0];
  const int*   src  = (const int*)d_in[1];
  const int*   dst  = (const int*)d_in[2];
  const float* W    = (const float*)d_in[4];
  const float* al   = (const float*)d_in[5];
  const float* ar   = (const float*)d_in[6];
  const float* Wm   = (const float*)d_in[7];
  const float* bm   = (const float*)d_in[8];
  float* out = (float*)d_out;
  (void)in_sizes; (void)n_in; (void)out_size; (void)ws_size;

  char* w = (char*)d_ws;
  size_t o = 0;
  auto take = [&](size_t bytes) -> void* {
    void* p = w + o;
    o += (bytes + 255) & ~(size_t)255;
    return p;
  };
  unsigned short* Btg = (unsigned short*)take((size_t)N_T * TILE_E * 2);         // 147 KB
  unsigned short* WmT = (unsigned short*)take((size_t)32 * 256 * 2);             // 16 KB
  unsigned short* ftg = (unsigned short*)take((size_t)N_T * N_NODES * HF * 2);   // 102.4 MB
  float* elg   = (float*)take((size_t)N_T * N_NODES * 4 * 4);                    // 6.4 MB
  float* erg   = (float*)take((size_t)N_T * N_NODES * 4 * 4);                    // 6.4 MB
  int*   cntb  = (int*)take((size_t)TN * 4);                                     // 1.6 MB
  int*   ofs   = (int*)take((size_t)TN * 4);
  int*   bsum  = (int*)take(4096);
  int*   rank  = (int*)take((size_t)TE * 4);                                     // 8 MB
  int*   bkt   = (int*)take((size_t)TE * 4);                                     // 8 MB
  int*   order = (int*)take((size_t)PAIRS * 4);                                  // 800 KB
  int*   gdh   = (int*)take(64 * 4);
  int*   dbase = (int*)take(64 * 4);
  int*   dcur  = (int*)take(64 * 4);
  unsigned short* aggb = (unsigned short*)take((size_t)(N_NODES + 64) * 256 * 2);// 51.2 MB

  hipMemsetAsync(cntb, 0, (size_t)TN * 4, stream);
  hipMemsetAsync(gdh,  0, 64 * 4, stream);
  hipMemsetAsync(dcur, 0, 64 * 4, stream);

  k_prep<<<34, 256, 0, stream>>>(W, al, ar, Wm, Btg, WmT);
  k_proj<<<1563, 256, 0, stream>>>(feat, Btg, ftg, elg, erg);
  k_hist<<<(TE + 255) / 256, 256, 0, stream>>>(dst, cntb, rank);
  k_scan1<<<NB1, 256, 0, stream>>>(cntb, ofs, bsum);
  k_scan2<<<1, 512, 0, stream>>>(bsum);
  k_scatter<<<(TE + 255) / 256, 256, 0, stream>>>(src, dst, ofs, bsum, rank, bkt);
  k_d1<<<NPBLK, 256, 0, stream>>>(cntb, gdh);
  k_d2<<<1, 64, 0, stream>>>(gdh, dbase);
  k_d3<<<NPBLK, 256, 0, stream>>>(cntb, dbase, dcur, order);
  k_gather<<<6250, 256, 0, stream>>>(order, bkt, ofs, cntb, bsum, elg, erg, (const uint4*)ftg, (uint4*)aggb);
  k_merge<<<1563, 256, 0, stream>>>(aggb, WmT, bm, out);
}

// Round 11
// 213.907 us; speedup vs baseline: 1.1227x; 1.1227x over previous
//
#include <hip/hip_runtime.h>

typedef short short8 __attribute__((ext_vector_type(8)));
typedef float f32x4 __attribute__((ext_vector_type(4)));
typedef unsigned int u32x4v __attribute__((ext_vector_type(4)));

#define N_NODES 100000
#define N_A     50000
#define N_EDGES 500000
#define N_T     4
#define D_IN    128
#define HF      128
#define BCOLS   144                  // 128 ft cols + 4 el + 4 er + 8 zero pad
#define TN      (N_T * N_NODES)
#define TE      (N_T * N_EDGES)
#define NB1     ((TN + 1023) / 1024) // 391 scan blocks
#define TILE_E  (BCOLS * D_IN)       // 18432 elems = 36864 B per (t) B-tile
#define LOG2E   1.44269504088896340736f

__device__ __forceinline__ unsigned short f2b(float f) {
  unsigned int u = __float_as_uint(f);
  u += 0x7FFFu + ((u >> 16) & 1u);
  return (unsigned short)(u >> 16);
}
__device__ __forceinline__ unsigned int pk2(float lo, float hi) {
  return (unsigned int)f2b(lo) | ((unsigned int)f2b(hi) << 16);
}
__device__ __forceinline__ float blo(unsigned int u) { return __uint_as_float(u << 16); }
__device__ __forceinline__ float bhi(unsigned int u) { return __uint_as_float(u & 0xFFFF0000u); }
// non-temporal stores: skip L2 allocate / RFO for streaming writes
__device__ __forceinline__ void nt_store_u4(uint4* p, uint4 v) {
  u32x4v t; t[0] = v.x; t[1] = v.y; t[2] = v.z; t[3] = v.w;
  __builtin_nontemporal_store(t, (u32x4v*)p);
}
__device__ __forceinline__ void nt_store_f(float* p, float v) {
  __builtin_nontemporal_store(v, p);
}
__device__ __forceinline__ void nt_store_i(int* p, int v) {
  __builtin_nontemporal_store(v, p);
}

// K0: fused prep. Blocks 0-1: Bt[t][144][128] bf16, XOR-swizzled
// ((j*128+k) ^ ((j&7)<<3)); rows 128..135 hold W@attn_{l,r} PRE-SCALED by
// log2(e) so gather can use exp2. Blocks 2-33: WmT (permuted-k merge weights).
__global__ __launch_bounds__(256) void k_prep(const float* __restrict__ W,
    const float* __restrict__ al, const float* __restrict__ ar,
    const float* __restrict__ Wm,
    unsigned short* __restrict__ Bt, unsigned short* __restrict__ WmT)
{
  if (blockIdx.x < 2) {
    int idx = blockIdx.x * 256 + threadIdx.x;
    int t = idx >> 7, k = idx & 127;
    const float* Wr = W + ((size_t)t * D_IN + k) * HF;
    unsigned short* o = Bt + (size_t)t * TILE_E;
    for (int j = 0; j < HF; ++j)
      o[(j * D_IN + k) ^ ((j & 7) << 3)] = f2b(Wr[j]);
    for (int h = 0; h < 4; ++h) {
      float sl = 0.f, sr = 0.f;
      const float* alh = al + (t * 4 + h) * 32;
      const float* arh = ar + (t * 4 + h) * 32;
      for (int f = 0; f < 32; ++f) { float w = Wr[h * 32 + f]; sl += w * alh[f]; sr += w * arh[f]; }
      int jl = 128 + h, jr = 132 + h;
      o[(jl * D_IN + k) ^ ((jl & 7) << 3)] = f2b(sl * LOG2E);
      o[(jr * D_IN + k) ^ ((jr & 7) << 3)] = f2b(sr * LOG2E);
    }
    for (int j = 136; j < 144; ++j)
      o[(j * D_IN + k) ^ ((j & 7) << 3)] = 0;
  } else {
    int idx = (blockIdx.x - 2) * 256 + threadIdx.x;
    int kidx = idx >> 5, j = idx & 31;
    int slot = kidx >> 7, p = kidx & 127;
    int col = (p & 7) * 16 + (p >> 3);
    WmT[j * 256 + kidx] = f2b(Wm[(slot * 128 + col) * 32 + j]);
  }
}

// K1: projection GEMM (proven shape). Block = 64 rows (4 waves x 16),
// grid 1563, launch_bounds(256,4) -> ~52 VGPR, no spill, 4 blocks/CU.
// ft / el / er written with non-temporal stores (pure streaming output).
__global__ __launch_bounds__(256, 4) void k_proj(const float* __restrict__ feat,
    const unsigned short* __restrict__ Btg,
    unsigned short* __restrict__ ftg,
    float* __restrict__ elg, float* __restrict__ erg)
{
  __shared__ __align__(16) unsigned short Bs[TILE_E];      // 36.8 KB -> 4 blocks/CU
  const int tid = threadIdx.x;
  const int wave = tid >> 6, lane = tid & 63;
  const int l15 = lane & 15, g = lane >> 4;
  const int wrow0 = blockIdx.x * 64 + wave * 16;

  short8 a[4];
  {
    int row = wrow0 + l15;
    const float* fr = feat + (size_t)(row < N_NODES ? row : N_NODES - 1) * D_IN;
#pragma unroll
    for (int kt = 0; kt < 4; ++kt) {
      float4 v0 = *(const float4*)(fr + kt * 32 + g * 8);
      float4 v1 = *(const float4*)(fr + kt * 32 + g * 8 + 4);
      short8 s;
      s[0] = (short)f2b(v0.x); s[1] = (short)f2b(v0.y);
      s[2] = (short)f2b(v0.z); s[3] = (short)f2b(v0.w);
      s[4] = (short)f2b(v1.x); s[5] = (short)f2b(v1.y);
      s[6] = (short)f2b(v1.z); s[7] = (short)f2b(v1.w);
      a[kt] = s;
    }
  }

  for (int t = 0; t < N_T; ++t) {
    if (t > 0) __syncthreads();
    {
      const uint4* src = (const uint4*)(Btg + (size_t)t * TILE_E);
      uint4* dstv = (uint4*)Bs;
#pragma unroll
      for (int i = 0; i < 9; ++i)
        dstv[i * 256 + tid] = src[i * 256 + tid];
    }
    __syncthreads();

    f32x4 acc[8];
#pragma unroll
    for (int ct = 0; ct < 8; ++ct) {
      f32x4 c = {0.f, 0.f, 0.f, 0.f};
#pragma unroll
      for (int kt = 0; kt < 4; ++kt) {
        int row = ct * 16 + l15;
        int boff = (row * 256 + kt * 64 + g * 16) ^ ((l15 & 7) << 4);
        short8 b = *(const short8*)((const char*)Bs + boff);
        c = __builtin_amdgcn_mfma_f32_16x16x32_bf16(a[kt], b, c, 0, 0, 0);
      }
      acc[ct] = c;
    }
    {
      f32x4 c8 = {0.f, 0.f, 0.f, 0.f};
#pragma unroll
      for (int kt = 0; kt < 4; ++kt) {
        int row = 128 + l15;
        int boff = (row * 256 + kt * 64 + g * 16) ^ ((l15 & 7) << 4);
        short8 b = *(const short8*)((const char*)Bs + boff);
        c8 = __builtin_amdgcn_mfma_f32_16x16x32_bf16(a[kt], b, c8, 0, 0, 0);
      }
      if (l15 < 8) {
#pragma unroll
        for (int r = 0; r < 4; ++r) {
          int row = wrow0 + g * 4 + r;
          if (row < N_NODES) {
            float v = c8[r];
            if (l15 < 4) nt_store_f(elg + ((size_t)t * N_NODES + row) * 4 + l15, v);
            else         nt_store_f(erg + ((size_t)t * N_NODES + row) * 4 + (l15 - 4), v);
          }
        }
      }
    }
#pragma unroll
    for (int r = 0; r < 4; ++r) {
      int row = wrow0 + g * 4 + r;
      if (row < N_NODES) {
        uint4 o;
        o.x = pk2(acc[0][r], acc[1][r]);
        o.y = pk2(acc[2][r], acc[3][r]);
        o.z = pk2(acc[4][r], acc[5][r]);
        o.w = pk2(acc[6][r], acc[7][r]);
        nt_store_u4((uint4*)(ftg + ((size_t)t * N_NODES + row) * HF + l15 * 8), o);
      }
    }
  }
}

// K2: histogram of kept edges by (t,dst) + per-edge within-bucket rank
__global__ __launch_bounds__(256) void k_hist(const int* __restrict__ dst,
    int* __restrict__ cnt, int* __restrict__ rank) {
  int idx = blockIdx.x * 256 + threadIdx.x;
  if (idx >= TE) return;
  int t = idx / N_EDGES;
  int d = dst[idx];
  bool keep = (t < 2) ? (d < N_A) : (d >= N_A);
  if (keep) nt_store_i(rank + idx, atomicAdd(&cnt[t * N_NODES + d], 1));
}

__global__ __launch_bounds__(256) void k_scan1(const int* __restrict__ cnt,
    int* __restrict__ ofs, int* __restrict__ bsum) {
  __shared__ int ts[256];
  int b = blockIdx.x, t = threadIdx.x;
  int base = b * 1024 + t * 4;
  int v0 = 0, v1 = 0, v2 = 0, v3 = 0;
  if (base + 0 < TN) v0 = cnt[base + 0];
  if (base + 1 < TN) v1 = cnt[base + 1];
  if (base + 2 < TN) v2 = cnt[base + 2];
  if (base + 3 < TN) v3 = cnt[base + 3];
  int s = v0 + v1 + v2 + v3;
  ts[t] = s;
  __syncthreads();
  for (int o = 1; o < 256; o <<= 1) {
    int x = (t >= o) ? ts[t - o] : 0;
    __syncthreads();
    ts[t] += x;
    __syncthreads();
  }
  int run = ts[t] - s;
  if (base + 0 < TN) ofs[base + 0] = run; run += v0;
  if (base + 1 < TN) ofs[base + 1] = run; run += v1;
  if (base + 2 < TN) ofs[base + 2] = run; run += v2;
  if (base + 3 < TN) ofs[base + 3] = run;
  if (t == 255) bsum[b] = ts[255];
}

__global__ __launch_bounds__(512) void k_scan2(int* __restrict__ bsum) {
  __shared__ int ts[512];
  int t = threadIdx.x;
  int v = (t < NB1) ? bsum[t] : 0;
  ts[t] = v;
  __syncthreads();
  for (int o = 1; o < 512; o <<= 1) {
    int x = (t >= o) ? ts[t - o] : 0;
    __syncthreads();
    ts[t] += x;
    __syncthreads();
  }
  if (t < NB1) bsum[t] = ts[t] - v;
}

// K3: slim scatter: 4 B record = src ft-row index; position from ofs+bsum+rank.
__global__ __launch_bounds__(256) void k_scatter(const int* __restrict__ src, const int* __restrict__ dst,
    const int* __restrict__ ofs, const int* __restrict__ bsum, const int* __restrict__ rank,
    int* __restrict__ bkt) {
  int idx = blockIdx.x * 256 + threadIdx.x;
  if (idx >= TE) return;
  int t = idx / N_EDGES;
  int d = dst[idx];
  bool keep = (t < 2) ? (d < N_A) : (d >= N_A);
  if (!keep) return;
  int key = t * N_NODES + d;
  int p = ofs[key] + bsum[key >> 10] + rank[idx];
  bkt[p] = t * N_NODES + src[idx];
}

// K4: gather (round-9 proven shape: consecutive pids -> contiguous stores).
// 8 pairs per wave, 8 lanes per pair. Per edge: 4 B record + 16 B el
// (broadcast) + 2x16 B ft; w[h] = exp2(fmax(s, 0.2s)), s pre-scaled by log2e.
// 2x unrolled; aggb written non-temporally (pure streaming output).
__global__ __launch_bounds__(256) void k_gather(const int* __restrict__ bkt,
    const int* __restrict__ ofs, const int* __restrict__ cnt, const int* __restrict__ bsum,
    const float* __restrict__ elg, const float* __restrict__ erg,
    const uint4* __restrict__ ftu, uint4* __restrict__ aggb)
{
  int wid = blockIdx.x * 4 + (threadIdx.x >> 6);
  int lane = threadIdx.x & 63;
  int g8 = lane >> 3, l7 = lane & 7;
  int pid = wid * 8 + g8;                      // pair id = node*2 + slot
  int n = pid >> 1, slot = pid & 1;
  int t = slot + ((n >= N_A) ? 2 : 0);
  int key = t * N_NODES + n;
  int base = ofs[key] + bsum[key >> 10];
  int c = cnt[key];
  float4 er4 = *(const float4*)(erg + (size_t)key * 4);
  float a00 = 0.f, a01 = 0.f, a02 = 0.f, a03 = 0.f, a04 = 0.f, a05 = 0.f, a06 = 0.f, a07 = 0.f;
  float a10 = 0.f, a11 = 0.f, a12 = 0.f, a13 = 0.f, a14 = 0.f, a15 = 0.f, a16 = 0.f, a17 = 0.f;
  float d0 = 0.f, d1 = 0.f, d2 = 0.f, d3 = 0.f;
  int qb = l7 * 2;
  int i = 0;
  for (; i + 1 < c; i += 2) {
    int s0 = bkt[base + i];
    int s1 = bkt[base + i + 1];
    float4 el0 = *(const float4*)(elg + (size_t)s0 * 4);
    float4 el1 = *(const float4*)(elg + (size_t)s1 * 4);
    uint4 u0a = ftu[(size_t)s0 * 16 + qb];
    uint4 u0b = ftu[(size_t)s0 * 16 + qb + 1];
    uint4 u1a = ftu[(size_t)s1 * 16 + qb];
    uint4 u1b = ftu[(size_t)s1 * 16 + qb + 1];
    float s, w0, w1, w2, w3;
    s = el0.x + er4.x; w0 = exp2f(fmaxf(s, 0.2f * s));
    s = el0.y + er4.y; w1 = exp2f(fmaxf(s, 0.2f * s));
    s = el0.z + er4.z; w2 = exp2f(fmaxf(s, 0.2f * s));
    s = el0.w + er4.w; w3 = exp2f(fmaxf(s, 0.2f * s));
    d0 += w0; d1 += w1; d2 += w2; d3 += w3;
    a00 += w0 * blo(u0a.x); a01 += w0 * bhi(u0a.x);
    a02 += w1 * blo(u0a.y); a03 += w1 * bhi(u0a.y);
    a04 += w2 * blo(u0a.z); a05 += w2 * bhi(u0a.z);
    a06 += w3 * blo(u0a.w); a07 += w3 * bhi(u0a.w);
    a10 += w0 * blo(u0b.x); a11 += w0 * bhi(u0b.x);
    a12 += w1 * blo(u0b.y); a13 += w1 * bhi(u0b.y);
    a14 += w2 * blo(u0b.z); a15 += w2 * bhi(u0b.z);
    a16 += w3 * blo(u0b.w); a17 += w3 * bhi(u0b.w);
    s = el1.x + er4.x; w0 = exp2f(fmaxf(s, 0.2f * s));
    s = el1.y + er4.y; w1 = exp2f(fmaxf(s, 0.2f * s));
    s = el1.z + er4.z; w2 = exp2f(fmaxf(s, 0.2f * s));
    s = el1.w + er4.w; w3 = exp2f(fmaxf(s, 0.2f * s));
    d0 += w0; d1 += w1; d2 += w2; d3 += w3;
    a00 += w0 * blo(u1a.x); a01 += w0 * bhi(u1a.x);
    a02 += w1 * blo(u1a.y); a03 += w1 * bhi(u1a.y);
    a04 += w2 * blo(u1a.z); a05 += w2 * bhi(u1a.z);
    a06 += w3 * blo(u1a.w); a07 += w3 * bhi(u1a.w);
    a10 += w0 * blo(u1b.x); a11 += w0 * bhi(u1b.x);
    a12 += w1 * blo(u1b.y); a13 += w1 * bhi(u1b.y);
    a14 += w2 * blo(u1b.z); a15 += w2 * bhi(u1b.z);
    a16 += w3 * blo(u1b.w); a17 += w3 * bhi(u1b.w);
  }
  if (i < c) {
    int s0 = bkt[base + i];
    float4 el0 = *(const float4*)(elg + (size_t)s0 * 4);
    uint4 u0a = ftu[(size_t)s0 * 16 + qb];
    uint4 u0b = ftu[(size_t)s0 * 16 + qb + 1];
    float s, w0, w1, w2, w3;
    s = el0.x + er4.x; w0 = exp2f(fmaxf(s, 0.2f * s));
    s = el0.y + er4.y; w1 = exp2f(fmaxf(s, 0.2f * s));
    s = el0.z + er4.z; w2 = exp2f(fmaxf(s, 0.2f * s));
    s = el0.w + er4.w; w3 = exp2f(fmaxf(s, 0.2f * s));
    d0 += w0; d1 += w1; d2 += w2; d3 += w3;
    a00 += w0 * blo(u0a.x); a01 += w0 * bhi(u0a.x);
    a02 += w1 * blo(u0a.y); a03 += w1 * bhi(u0a.y);
    a04 += w2 * blo(u0a.z); a05 += w2 * bhi(u0a.z);
    a06 += w3 * blo(u0a.w); a07 += w3 * bhi(u0a.w);
    a10 += w0 * blo(u0b.x); a11 += w0 * bhi(u0b.x);
    a12 += w1 * blo(u0b.y); a13 += w1 * bhi(u0b.y);
    a14 += w2 * blo(u0b.z); a15 += w2 * bhi(u0b.z);
    a16 += w3 * blo(u0b.w); a17 += w3 * bhi(u0b.w);
  }
  float i0 = (c > 0) ? 1.f / d0 : 0.f;
  float i1 = (c > 0) ? 1.f / d1 : 0.f;
  float i2 = (c > 0) ? 1.f / d2 : 0.f;
  float i3 = (c > 0) ? 1.f / d3 : 0.f;
  uint4 oA, oB;
  oA.x = pk2(a00 * i0, a01 * i0);
  oA.y = pk2(a02 * i1, a03 * i1);
  oA.z = pk2(a04 * i2, a05 * i2);
  oA.w = pk2(a06 * i3, a07 * i3);
  oB.x = pk2(a10 * i0, a11 * i0);
  oB.y = pk2(a12 * i1, a13 * i1);
  oB.z = pk2(a14 * i2, a15 * i2);
  oB.w = pk2(a16 * i3, a17 * i3);
  size_t ob = (size_t)n * 32 + slot * 16 + qb;
  nt_store_u4(&aggb[ob], oA);
  nt_store_u4(&aggb[ob + 1], oB);
}

// K5: merge GEMM via MFMA. 64 nodes/block, out = agg(bf16, permuted-k) @ WmT + bm.
__global__ __launch_bounds__(256) void k_merge(const unsigned short* __restrict__ aggb,
    const unsigned short* __restrict__ WmT, const float* __restrict__ bm,
    float* __restrict__ out)
{
  __shared__ __align__(16) unsigned short Al[64 * 264];
  __shared__ __align__(16) unsigned short Bl[32 * 264];
  int n0 = blockIdx.x * 64;
  int tid = threadIdx.x;
  const uint4* asrc = (const uint4*)(aggb + (size_t)n0 * 256);
  for (int i = tid; i < 2048; i += 256) {
    int r = i >> 5, c = i & 31;
    *(uint4*)&Al[r * 264 + c * 8] = asrc[r * 32 + c];
  }
  for (int i = tid; i < 1024; i += 256) {
    int r = i >> 5, c = i & 31;
    *(uint4*)&Bl[r * 264 + c * 8] = ((const uint4*)WmT)[r * 32 + c];
  }
  __syncthreads();
  int wave = tid >> 6, lane = tid & 63;
  int l15 = lane & 15, lk = (lane >> 4) * 8;
  short8 a[8];
#pragma unroll
  for (int kt = 0; kt < 8; ++kt)
    a[kt] = *(const short8*)&Al[(wave * 16 + l15) * 264 + kt * 32 + lk];
  f32x4 acc0 = {0.f, 0.f, 0.f, 0.f}, acc1 = {0.f, 0.f, 0.f, 0.f};
#pragma unroll
  for (int kt = 0; kt < 8; ++kt) {
    short8 b0 = *(const short8*)&Bl[l15 * 264 + kt * 32 + lk];
    short8 b1 = *(const short8*)&Bl[(16 + l15) * 264 + kt * 32 + lk];
    acc0 = __builtin_amdgcn_mfma_f32_16x16x32_bf16(a[kt], b0, acc0, 0, 0, 0);
    acc1 = __builtin_amdgcn_mfma_f32_16x16x32_bf16(a[kt], b1, acc1, 0, 0, 0);
  }
  float bm0 = bm[l15], bm1 = bm[16 + l15];
#pragma unroll
  for (int r = 0; r < 4; ++r) {
    int row = n0 + wave * 16 + (lane >> 4) * 4 + r;
    if (row < N_NODES) {
      nt_store_f(out + (size_t)row * 32 + l15, acc0[r] + bm0);
      nt_store_f(out + (size_t)row * 32 + 16 + l15, acc1[r] + bm1);
    }
  }
}

extern "C" void kernel_launch(void* const* d_in, const int* in_sizes, int n_in,
                              void* d_out, int out_size, void* d_ws, size_t ws_size,
                              hipStream_t stream)
{
  const float* feat = (const float*)d_in[0];
  const int*   src  = (const int*)d_in[1];
  const int*   dst  = (const int*)d_in[2];
  const float* W    = (const float*)d_in[4];
  const float* al   = (const float*)d_in[5];
  const float* ar   = (const float*)d_in[6];
  const float* Wm   = (const float*)d_in[7];
  const float* bm   = (const float*)d_in[8];
  float* out = (float*)d_out;
  (void)in_sizes; (void)n_in; (void)out_size; (void)ws_size;

  char* w = (char*)d_ws;
  size_t o = 0;
  auto take = [&](size_t bytes) -> void* {
    void* p = w + o;
    o += (bytes + 255) & ~(size_t)255;
    return p;
  };
  unsigned short* Btg = (unsigned short*)take((size_t)N_T * TILE_E * 2);         // 147 KB
  unsigned short* WmT = (unsigned short*)take((size_t)32 * 256 * 2);             // 16 KB
  unsigned short* ftg = (unsigned short*)take((size_t)N_T * N_NODES * HF * 2);   // 102.4 MB
  float* elg   = (float*)take((size_t)N_T * N_NODES * 4 * 4);                    // 6.4 MB
  float* erg   = (float*)take((size_t)N_T * N_NODES * 4 * 4);                    // 6.4 MB
  int*   cntb  = (int*)take((size_t)TN * 4);                                     // 1.6 MB
  int*   ofs   = (int*)take((size_t)TN * 4);
  int*   bsum  = (int*)take(4096);
  int*   rank  = (int*)take((size_t)TE * 4);                                     // 8 MB
  int*   bkt   = (int*)take((size_t)TE * 4);                                     // 8 MB
  unsigned short* aggb = (unsigned short*)take((size_t)(N_NODES + 64) * 256 * 2);// 51.2 MB

  hipMemsetAsync(cntb, 0, (size_t)TN * 4, stream);

  k_prep<<<34, 256, 0, stream>>>(W, al, ar, Wm, Btg, WmT);
  k_proj<<<1563, 256, 0, stream>>>(feat, Btg, ftg, elg, erg);
  k_hist<<<(TE + 255) / 256, 256, 0, stream>>>(dst, cntb, rank);
  k_scan1<<<NB1, 256, 0, stream>>>(cntb, ofs, bsum);
  k_scan2<<<1, 512, 0, stream>>>(bsum);
  k_scatter<<<(TE + 255) / 256, 256, 0, stream>>>(src, dst, ofs, bsum, rank, bkt);
  k_gather<<<6250, 256, 0, stream>>>(bkt, ofs, cntb, bsum, elg, erg, (const uint4*)ftg, (uint4*)aggb);
  k_merge<<<1563, 256, 0, stream>>>(aggb, WmT, bm, out);
}

// Round 13
// 203.472 us; speedup vs baseline: 1.1803x; 1.0513x over previous
//
#include <hip/hip_runtime.h>
#include <hip/hip_fp16.h>

typedef short short8 __attribute__((ext_vector_type(8)));
typedef _Float16 half8 __attribute__((ext_vector_type(8)));
typedef float f32x4 __attribute__((ext_vector_type(4)));

#define N_NODES 100000
#define N_A     50000
#define N_EDGES 500000
#define N_T     4
#define D_IN    128
#define HF      128
#define BCOLS   144                  // 128 ft cols + 4 el + 4 er + 8 zero pad
#define TN      (N_T * N_NODES)
#define TE      (N_T * N_EDGES)
#define NB1     ((TN + 1023) / 1024) // 391 scan blocks
#define TILE_E  (BCOLS * D_IN)       // 18432 elems = 36864 B per (t) B-tile
#define LOG2E   1.44269504088896340736f

__device__ __forceinline__ unsigned short f2b(float f) {
  unsigned int u = __float_as_uint(f);
  u += 0x7FFFu + ((u >> 16) & 1u);
  return (unsigned short)(u >> 16);
}
// f32 pair -> packed f16 word (v_cvt_pkrtz_f16_f32, 1 instruction)
__device__ __forceinline__ unsigned int pkh(float lo, float hi) {
  auto v = __builtin_amdgcn_cvt_pkrtz(lo, hi);
  unsigned int u; __builtin_memcpy(&u, &v, 4); return u;
}
__device__ __forceinline__ unsigned short f2h(float f) {
  auto v = __builtin_amdgcn_cvt_pkrtz(f, 0.f);
  unsigned int u; __builtin_memcpy(&u, &v, 4); return (unsigned short)(u & 0xFFFFu);
}
__device__ __forceinline__ __half2 w2h(unsigned int u) {
  __half2 h; __builtin_memcpy(&h, &u, 4); return h;
}
__device__ __forceinline__ unsigned int h2w(__half2 h) {
  unsigned int u; __builtin_memcpy(&u, &h, 4); return u;
}

// K0: fused prep. Blocks 0-1: Bt[t][144][128] bf16 (proj MFMA B-side),
// XOR-swizzled ((j*128+k) ^ ((j&7)<<3)); rows 128..135 = W@attn_{l,r}
// PRE-SCALED by log2(e). Blocks 2-33: WmT in F16 (permuted-k merge weights).
__global__ __launch_bounds__(256) void k_prep(const float* __restrict__ W,
    const float* __restrict__ al, const float* __restrict__ ar,
    const float* __restrict__ Wm,
    unsigned short* __restrict__ Bt, unsigned short* __restrict__ WmT)
{
  if (blockIdx.x < 2) {
    int idx = blockIdx.x * 256 + threadIdx.x;
    int t = idx >> 7, k = idx & 127;
    const float* Wr = W + ((size_t)t * D_IN + k) * HF;
    unsigned short* o = Bt + (size_t)t * TILE_E;
    for (int j = 0; j < HF; ++j)
      o[(j * D_IN + k) ^ ((j & 7) << 3)] = f2b(Wr[j]);
    for (int h = 0; h < 4; ++h) {
      float sl = 0.f, sr = 0.f;
      const float* alh = al + (t * 4 + h) * 32;
      const float* arh = ar + (t * 4 + h) * 32;
      for (int f = 0; f < 32; ++f) { float w = Wr[h * 32 + f]; sl += w * alh[f]; sr += w * arh[f]; }
      int jl = 128 + h, jr = 132 + h;
      o[(jl * D_IN + k) ^ ((jl & 7) << 3)] = f2b(sl * LOG2E);
      o[(jr * D_IN + k) ^ ((jr & 7) << 3)] = f2b(sr * LOG2E);
    }
    for (int j = 136; j < 144; ++j)
      o[(j * D_IN + k) ^ ((j & 7) << 3)] = 0;
  } else {
    int idx = (blockIdx.x - 2) * 256 + threadIdx.x;
    int kidx = idx >> 5, j = idx & 31;
    int slot = kidx >> 7, p = kidx & 127;
    int col = (p & 7) * 16 + (p >> 3);
    WmT[j * 256 + kidx] = f2h(Wm[(slot * 128 + col) * 32 + j]);
  }
}

// K1: projection GEMM (proven shape). Block = 64 rows (4 waves x 16),
// grid 1563, launch_bounds(256,4). ft written in permuted layout as F16.
__global__ __launch_bounds__(256, 4) void k_proj(const float* __restrict__ feat,
    const unsigned short* __restrict__ Btg,
    unsigned short* __restrict__ ftg,
    float* __restrict__ elg, float* __restrict__ erg)
{
  __shared__ __align__(16) unsigned short Bs[TILE_E];      // 36.8 KB -> 4 blocks/CU
  const int tid = threadIdx.x;
  const int wave = tid >> 6, lane = tid & 63;
  const int l15 = lane & 15, g = lane >> 4;
  const int wrow0 = blockIdx.x * 64 + wave * 16;

  short8 a[4];
  {
    int row = wrow0 + l15;
    const float* fr = feat + (size_t)(row < N_NODES ? row : N_NODES - 1) * D_IN;
#pragma unroll
    for (int kt = 0; kt < 4; ++kt) {
      float4 v0 = *(const float4*)(fr + kt * 32 + g * 8);
      float4 v1 = *(const float4*)(fr + kt * 32 + g * 8 + 4);
      short8 s;
      s[0] = (short)f2b(v0.x); s[1] = (short)f2b(v0.y);
      s[2] = (short)f2b(v0.z); s[3] = (short)f2b(v0.w);
      s[4] = (short)f2b(v1.x); s[5] = (short)f2b(v1.y);
      s[6] = (short)f2b(v1.z); s[7] = (short)f2b(v1.w);
      a[kt] = s;
    }
  }

  for (int t = 0; t < N_T; ++t) {
    if (t > 0) __syncthreads();
    {
      const uint4* src = (const uint4*)(Btg + (size_t)t * TILE_E);
      uint4* dstv = (uint4*)Bs;
#pragma unroll
      for (int i = 0; i < 9; ++i)
        dstv[i * 256 + tid] = src[i * 256 + tid];
    }
    __syncthreads();

    f32x4 acc[8];
#pragma unroll
    for (int ct = 0; ct < 8; ++ct) {
      f32x4 c = {0.f, 0.f, 0.f, 0.f};
#pragma unroll
      for (int kt = 0; kt < 4; ++kt) {
        int row = ct * 16 + l15;
        int boff = (row * 256 + kt * 64 + g * 16) ^ ((l15 & 7) << 4);
        short8 b = *(const short8*)((const char*)Bs + boff);
        c = __builtin_amdgcn_mfma_f32_16x16x32_bf16(a[kt], b, c, 0, 0, 0);
      }
      acc[ct] = c;
    }
    {
      f32x4 c8 = {0.f, 0.f, 0.f, 0.f};
#pragma unroll
      for (int kt = 0; kt < 4; ++kt) {
        int row = 128 + l15;
        int boff = (row * 256 + kt * 64 + g * 16) ^ ((l15 & 7) << 4);
        short8 b = *(const short8*)((const char*)Bs + boff);
        c8 = __builtin_amdgcn_mfma_f32_16x16x32_bf16(a[kt], b, c8, 0, 0, 0);
      }
      if (l15 < 8) {
#pragma unroll
        for (int r = 0; r < 4; ++r) {
          int row = wrow0 + g * 4 + r;
          if (row < N_NODES) {
            float v = c8[r];
            if (l15 < 4) elg[((size_t)t * N_NODES + row) * 4 + l15] = v;
            else         erg[((size_t)t * N_NODES + row) * 4 + (l15 - 4)] = v;
          }
        }
      }
    }
    // direct permuted ft store (F16): row-position p = l15*8 + ct
#pragma unroll
    for (int r = 0; r < 4; ++r) {
      int row = wrow0 + g * 4 + r;
      if (row < N_NODES) {
        uint4 o;
        o.x = pkh(acc[0][r], acc[1][r]);
        o.y = pkh(acc[2][r], acc[3][r]);
        o.z = pkh(acc[4][r], acc[5][r]);
        o.w = pkh(acc[6][r], acc[7][r]);
        *(uint4*)(ftg + ((size_t)t * N_NODES + row) * HF + l15 * 8) = o;
      }
    }
  }
}

// K2: histogram of kept edges by (t,dst) + per-edge within-bucket rank
__global__ __launch_bounds__(256) void k_hist(const int* __restrict__ dst,
    int* __restrict__ cnt, int* __restrict__ rank) {
  int idx = blockIdx.x * 256 + threadIdx.x;
  if (idx >= TE) return;
  int t = idx / N_EDGES;
  int d = dst[idx];
  bool keep = (t < 2) ? (d < N_A) : (d >= N_A);
  if (keep) rank[idx] = atomicAdd(&cnt[t * N_NODES + d], 1);
}

__global__ __launch_bounds__(256) void k_scan1(const int* __restrict__ cnt,
    int* __restrict__ ofs, int* __restrict__ bsum) {
  __shared__ int ts[256];
  int b = blockIdx.x, t = threadIdx.x;
  int base = b * 1024 + t * 4;
  int v0 = 0, v1 = 0, v2 = 0, v3 = 0;
  if (base + 0 < TN) v0 = cnt[base + 0];
  if (base + 1 < TN) v1 = cnt[base + 1];
  if (base + 2 < TN) v2 = cnt[base + 2];
  if (base + 3 < TN) v3 = cnt[base + 3];
  int s = v0 + v1 + v2 + v3;
  ts[t] = s;
  __syncthreads();
  for (int o = 1; o < 256; o <<= 1) {
    int x = (t >= o) ? ts[t - o] : 0;
    __syncthreads();
    ts[t] += x;
    __syncthreads();
  }
  int run = ts[t] - s;
  if (base + 0 < TN) ofs[base + 0] = run; run += v0;
  if (base + 1 < TN) ofs[base + 1] = run; run += v1;
  if (base + 2 < TN) ofs[base + 2] = run; run += v2;
  if (base + 3 < TN) ofs[base + 3] = run;
  if (t == 255) bsum[b] = ts[255];
}

__global__ __launch_bounds__(512) void k_scan2(int* __restrict__ bsum) {
  __shared__ int ts[512];
  int t = threadIdx.x;
  int v = (t < NB1) ? bsum[t] : 0;
  ts[t] = v;
  __syncthreads();
  for (int o = 1; o < 512; o <<= 1) {
    int x = (t >= o) ? ts[t - o] : 0;
    __syncthreads();
    ts[t] += x;
    __syncthreads();
  }
  if (t < NB1) bsum[t] = ts[t] - v;
}

// K3: slim scatter: 4 B record = src ft-row index; position from ofs+bsum+rank.
__global__ __launch_bounds__(256) void k_scatter(const int* __restrict__ src, const int* __restrict__ dst,
    const int* __restrict__ ofs, const int* __restrict__ bsum, const int* __restrict__ rank,
    int* __restrict__ bkt) {
  int idx = blockIdx.x * 256 + threadIdx.x;
  if (idx >= TE) return;
  int t = idx / N_EDGES;
  int d = dst[idx];
  bool keep = (t < 2) ? (d < N_A) : (d >= N_A);
  if (!keep) return;
  int key = t * N_NODES + d;
  int p = ofs[key] + bsum[key >> 10] + rank[idx];
  bkt[p] = t * N_NODES + src[idx];
}

// K4: gather (round-9 shape: consecutive pids). 8 pairs/wave, 8 lanes/pair.
// ft is F16 -> accumulate with v_pk_fma_f16 (__hfma2): 8 packed FMAs/edge
// instead of 16 unpack+FMA chains. Weights f32 exp2(fmax(s,0.2s)), s
// pre-scaled by log2e; per-head half2 broadcast. den stays f32.
__global__ __launch_bounds__(256) void k_gather(const int* __restrict__ bkt,
    const int* __restrict__ ofs, const int* __restrict__ cnt, const int* __restrict__ bsum,
    const float* __restrict__ elg, const float* __restrict__ erg,
    const uint4* __restrict__ ftu, uint4* __restrict__ aggb)
{
  int wid = blockIdx.x * 4 + (threadIdx.x >> 6);
  int lane = threadIdx.x & 63;
  int g8 = lane >> 3, l7 = lane & 7;
  int pid = wid * 8 + g8;                      // pair id = node*2 + slot
  int n = pid >> 1, slot = pid & 1;
  int t = slot + ((n >= N_A) ? 2 : 0);
  int key = t * N_NODES + n;
  int base = ofs[key] + bsum[key >> 10];
  int c = cnt[key];
  float4 er4 = *(const float4*)(erg + (size_t)key * 4);
  __half2 A0 = __float2half2_rn(0.f), A1 = A0, A2 = A0, A3 = A0;
  __half2 B0 = A0, B1 = A0, B2 = A0, B3 = A0;
  float d0 = 0.f, d1 = 0.f, d2 = 0.f, d3 = 0.f;
  int qb = l7 * 2;
  int i = 0;
  for (; i + 1 < c; i += 2) {
    int s0 = bkt[base + i];
    int s1 = bkt[base + i + 1];
    float4 el0 = *(const float4*)(elg + (size_t)s0 * 4);
    float4 el1 = *(const float4*)(elg + (size_t)s1 * 4);
    uint4 u0a = ftu[(size_t)s0 * 16 + qb];
    uint4 u0b = ftu[(size_t)s0 * 16 + qb + 1];
    uint4 u1a = ftu[(size_t)s1 * 16 + qb];
    uint4 u1b = ftu[(size_t)s1 * 16 + qb + 1];
    float s, w0, w1, w2, w3;
    s = el0.x + er4.x; w0 = exp2f(fmaxf(s, 0.2f * s));
    s = el0.y + er4.y; w1 = exp2f(fmaxf(s, 0.2f * s));
    s = el0.z + er4.z; w2 = exp2f(fmaxf(s, 0.2f * s));
    s = el0.w + er4.w; w3 = exp2f(fmaxf(s, 0.2f * s));
    d0 += w0; d1 += w1; d2 += w2; d3 += w3;
    {
      __half2 h0 = __float2half2_rn(w0), h1 = __float2half2_rn(w1);
      __half2 h2 = __float2half2_rn(w2), h3 = __float2half2_rn(w3);
      A0 = __hfma2(w2h(u0a.x), h0, A0); A1 = __hfma2(w2h(u0a.y), h1, A1);
      A2 = __hfma2(w2h(u0a.z), h2, A2); A3 = __hfma2(w2h(u0a.w), h3, A3);
      B0 = __hfma2(w2h(u0b.x), h0, B0); B1 = __hfma2(w2h(u0b.y), h1, B1);
      B2 = __hfma2(w2h(u0b.z), h2, B2); B3 = __hfma2(w2h(u0b.w), h3, B3);
    }
    s = el1.x + er4.x; w0 = exp2f(fmaxf(s, 0.2f * s));
    s = el1.y + er4.y; w1 = exp2f(fmaxf(s, 0.2f * s));
    s = el1.z + er4.z; w2 = exp2f(fmaxf(s, 0.2f * s));
    s = el1.w + er4.w; w3 = exp2f(fmaxf(s, 0.2f * s));
    d0 += w0; d1 += w1; d2 += w2; d3 += w3;
    {
      __half2 h0 = __float2half2_rn(w0), h1 = __float2half2_rn(w1);
      __half2 h2 = __float2half2_rn(w2), h3 = __float2half2_rn(w3);
      A0 = __hfma2(w2h(u1a.x), h0, A0); A1 = __hfma2(w2h(u1a.y), h1, A1);
      A2 = __hfma2(w2h(u1a.z), h2, A2); A3 = __hfma2(w2h(u1a.w), h3, A3);
      B0 = __hfma2(w2h(u1b.x), h0, B0); B1 = __hfma2(w2h(u1b.y), h1, B1);
      B2 = __hfma2(w2h(u1b.z), h2, B2); B3 = __hfma2(w2h(u1b.w), h3, B3);
    }
  }
  if (i < c) {
    int s0 = bkt[base + i];
    float4 el0 = *(const float4*)(elg + (size_t)s0 * 4);
    uint4 u0a = ftu[(size_t)s0 * 16 + qb];
    uint4 u0b = ftu[(size_t)s0 * 16 + qb + 1];
    float s, w0, w1, w2, w3;
    s = el0.x + er4.x; w0 = exp2f(fmaxf(s, 0.2f * s));
    s = el0.y + er4.y; w1 = exp2f(fmaxf(s, 0.2f * s));
    s = el0.z + er4.z; w2 = exp2f(fmaxf(s, 0.2f * s));
    s = el0.w + er4.w; w3 = exp2f(fmaxf(s, 0.2f * s));
    d0 += w0; d1 += w1; d2 += w2; d3 += w3;
    __half2 h0 = __float2half2_rn(w0), h1 = __float2half2_rn(w1);
    __half2 h2 = __float2half2_rn(w2), h3 = __float2half2_rn(w3);
    A0 = __hfma2(w2h(u0a.x), h0, A0); A1 = __hfma2(w2h(u0a.y), h1, A1);
    A2 = __hfma2(w2h(u0a.z), h2, A2); A3 = __hfma2(w2h(u0a.w), h3, A3);
    B0 = __hfma2(w2h(u0b.x), h0, B0); B1 = __hfma2(w2h(u0b.y), h1, B1);
    B2 = __hfma2(w2h(u0b.z), h2, B2); B3 = __hfma2(w2h(u0b.w), h3, B3);
  }
  __half2 i0 = __float2half2_rn((c > 0) ? 1.f / d0 : 0.f);
  __half2 i1 = __float2half2_rn((c > 0) ? 1.f / d1 : 0.f);
  __half2 i2 = __float2half2_rn((c > 0) ? 1.f / d2 : 0.f);
  __half2 i3 = __float2half2_rn((c > 0) ? 1.f / d3 : 0.f);
  uint4 oA, oB;
  oA.x = h2w(__hmul2(A0, i0)); oA.y = h2w(__hmul2(A1, i1));
  oA.z = h2w(__hmul2(A2, i2)); oA.w = h2w(__hmul2(A3, i3));
  oB.x = h2w(__hmul2(B0, i0)); oB.y = h2w(__hmul2(B1, i1));
  oB.z = h2w(__hmul2(B2, i2)); oB.w = h2w(__hmul2(B3, i3));
  size_t ob = (size_t)n * 32 + slot * 16 + qb;
  aggb[ob] = oA;
  aggb[ob + 1] = oB;
}

// K5: merge GEMM via F16 MFMA. 64 nodes/block, out = agg(f16, permuted-k) @ WmT + bm.
__global__ __launch_bounds__(256) void k_merge(const unsigned short* __restrict__ aggb,
    const unsigned short* __restrict__ WmT, const float* __restrict__ bm,
    float* __restrict__ out)
{
  __shared__ __align__(16) unsigned short Al[64 * 264];
  __shared__ __align__(16) unsigned short Bl[32 * 264];
  int n0 = blockIdx.x * 64;
  int tid = threadIdx.x;
  const uint4* asrc = (const uint4*)(aggb + (size_t)n0 * 256);
  for (int i = tid; i < 2048; i += 256) {
    int r = i >> 5, c = i & 31;
    *(uint4*)&Al[r * 264 + c * 8] = asrc[r * 32 + c];
  }
  for (int i = tid; i < 1024; i += 256) {
    int r = i >> 5, c = i & 31;
    *(uint4*)&Bl[r * 264 + c * 8] = ((const uint4*)WmT)[r * 32 + c];
  }
  __syncthreads();
  int wave = tid >> 6, lane = tid & 63;
  int l15 = lane & 15, lk = (lane >> 4) * 8;
  half8 a[8];
#pragma unroll
  for (int kt = 0; kt < 8; ++kt)
    a[kt] = *(const half8*)&Al[(wave * 16 + l15) * 264 + kt * 32 + lk];
  f32x4 acc0 = {0.f, 0.f, 0.f, 0.f}, acc1 = {0.f, 0.f, 0.f, 0.f};
#pragma unroll
  for (int kt = 0; kt < 8; ++kt) {
    half8 b0 = *(const half8*)&Bl[l15 * 264 + kt * 32 + lk];
    half8 b1 = *(const half8*)&Bl[(16 + l15) * 264 + kt * 32 + lk];
    acc0 = __builtin_amdgcn_mfma_f32_16x16x32_f16(a[kt], b0, acc0, 0, 0, 0);
    acc1 = __builtin_amdgcn_mfma_f32_16x16x32_f16(a[kt], b1, acc1, 0, 0, 0);
  }
  float bm0 = bm[l15], bm1 = bm[16 + l15];
#pragma unroll
  for (int r = 0; r < 4; ++r) {
    int row = n0 + wave * 16 + (lane >> 4) * 4 + r;
    if (row < N_NODES) {
      out[(size_t)row * 32 + l15] = acc0[r] + bm0;
      out[(size_t)row * 32 + 16 + l15] = acc1[r] + bm1;
    }
  }
}

extern "C" void kernel_launch(void* const* d_in, const int* in_sizes, int n_in,
                              void* d_out, int out_size, void* d_ws, size_t ws_size,
                              hipStream_t stream)
{
  const float* feat = (const float*)d_in[0];
  const int*   src  = (const int*)d_in[1];
  const int*   dst  = (const int*)d_in[2];
  const float* W    = (const float*)d_in[4];
  const float* al   = (const float*)d_in[5];
  const float* ar   = (const float*)d_in[6];
  const float* Wm   = (const float*)d_in[7];
  const float* bm   = (const float*)d_in[8];
  float* out = (float*)d_out;
  (void)in_sizes; (void)n_in; (void)out_size; (void)ws_size;

  char* w = (char*)d_ws;
  size_t o = 0;
  auto take = [&](size_t bytes) -> void* {
    void* p = w + o;
    o += (bytes + 255) & ~(size_t)255;
    return p;
  };
  unsigned short* Btg = (unsigned short*)take((size_t)N_T * TILE_E * 2);         // 147 KB
  unsigned short* WmT = (unsigned short*)take((size_t)32 * 256 * 2);             // 16 KB
  unsigned short* ftg = (unsigned short*)take((size_t)N_T * N_NODES * HF * 2);   // 102.4 MB
  float* elg   = (float*)take((size_t)N_T * N_NODES * 4 * 4);                    // 6.4 MB
  float* erg   = (float*)take((size_t)N_T * N_NODES * 4 * 4);                    // 6.4 MB
  int*   cntb  = (int*)take((size_t)TN * 4);                                     // 1.6 MB
  int*   ofs   = (int*)take((size_t)TN * 4);
  int*   bsum  = (int*)take(4096);
  int*   rank  = (int*)take((size_t)TE * 4);                                     // 8 MB
  int*   bkt   = (int*)take((size_t)TE * 4);                                     // 8 MB
  unsigned short* aggb = (unsigned short*)take((size_t)(N_NODES + 64) * 256 * 2);// 51.2 MB

  hipMemsetAsync(cntb, 0, (size_t)TN * 4, stream);

  k_prep<<<34, 256, 0, stream>>>(W, al, ar, Wm, Btg, WmT);
  k_proj<<<1563, 256, 0, stream>>>(feat, Btg, ftg, elg, erg);
  k_hist<<<(TE + 255) / 256, 256, 0, stream>>>(dst, cntb, rank);
  k_scan1<<<NB1, 256, 0, stream>>>(cntb, ofs, bsum);
  k_scan2<<<1, 512, 0, stream>>>(bsum);
  k_scatter<<<(TE + 255) / 256, 256, 0, stream>>>(src, dst, ofs, bsum, rank, bkt);
  k_gather<<<6250, 256, 0, stream>>>(bkt, ofs, cntb, bsum, elg, erg, (const uint4*)ftg, (uint4*)aggb);
  k_merge<<<1563, 256, 0, stream>>>(aggb, WmT, bm, out);
}

// Round 14
// 197.238 us; speedup vs baseline: 1.2176x; 1.0316x over previous
//
#include <hip/hip_runtime.h>
#include <hip/hip_fp16.h>

typedef short short8 __attribute__((ext_vector_type(8)));
typedef _Float16 half8 __attribute__((ext_vector_type(8)));
typedef float f32x4 __attribute__((ext_vector_type(4)));

#define N_NODES 100000
#define N_A     50000
#define N_EDGES 500000
#define N_T     4
#define D_IN    128
#define HF      128
#define BCOLS   144                  // 128 ft cols + 4 el + 4 er + 8 zero pad
#define TN      (N_T * N_NODES)
#define TE      (N_T * N_EDGES)
#define NB1     ((TN + 1023) / 1024) // 391 scan blocks
#define TILE_E  (BCOLS * D_IN)       // 18432 elems = 36864 B per (t) B-tile
#define LOG2E   1.44269504088896340736f
#define NPROJB  1563
#define NHISTB  ((TE + 255) / 256)   // 7813

__device__ __forceinline__ unsigned short f2b(float f) {
  unsigned int u = __float_as_uint(f);
  u += 0x7FFFu + ((u >> 16) & 1u);
  return (unsigned short)(u >> 16);
}
// f32 pair -> packed f16 word (v_cvt_pkrtz_f16_f32, 1 instruction)
__device__ __forceinline__ unsigned int pkh(float lo, float hi) {
  auto v = __builtin_amdgcn_cvt_pkrtz(lo, hi);
  unsigned int u; __builtin_memcpy(&u, &v, 4); return u;
}
__device__ __forceinline__ unsigned short f2h(float f) {
  auto v = __builtin_amdgcn_cvt_pkrtz(f, 0.f);
  unsigned int u; __builtin_memcpy(&u, &v, 4); return (unsigned short)(u & 0xFFFFu);
}
__device__ __forceinline__ __half2 w2h(unsigned int u) {
  __half2 h; __builtin_memcpy(&h, &u, 4); return h;
}
__device__ __forceinline__ unsigned int h2w(__half2 h) {
  unsigned int u; __builtin_memcpy(&u, &h, 4); return u;
}

// K0: fused prep. Blocks 0-1: Bt[t][144][128] bf16 (proj MFMA B-side),
// XOR-swizzled ((j*128+k) ^ ((j&7)<<3)); rows 128..135 = W@attn_{l,r}
// PRE-SCALED by log2(e). Blocks 2-33: WmT in F16 (permuted-k merge weights).
__global__ __launch_bounds__(256) void k_prep(const float* __restrict__ W,
    const float* __restrict__ al, const float* __restrict__ ar,
    const float* __restrict__ Wm,
    unsigned short* __restrict__ Bt, unsigned short* __restrict__ WmT)
{
  if (blockIdx.x < 2) {
    int idx = blockIdx.x * 256 + threadIdx.x;
    int t = idx >> 7, k = idx & 127;
    const float* Wr = W + ((size_t)t * D_IN + k) * HF;
    unsigned short* o = Bt + (size_t)t * TILE_E;
    for (int j = 0; j < HF; ++j)
      o[(j * D_IN + k) ^ ((j & 7) << 3)] = f2b(Wr[j]);
    for (int h = 0; h < 4; ++h) {
      float sl = 0.f, sr = 0.f;
      const float* alh = al + (t * 4 + h) * 32;
      const float* arh = ar + (t * 4 + h) * 32;
      for (int f = 0; f < 32; ++f) { float w = Wr[h * 32 + f]; sl += w * alh[f]; sr += w * arh[f]; }
      int jl = 128 + h, jr = 132 + h;
      o[(jl * D_IN + k) ^ ((jl & 7) << 3)] = f2b(sl * LOG2E);
      o[(jr * D_IN + k) ^ ((jr & 7) << 3)] = f2b(sr * LOG2E);
    }
    for (int j = 136; j < 144; ++j)
      o[(j * D_IN + k) ^ ((j & 7) << 3)] = 0;
  } else {
    int idx = (blockIdx.x - 2) * 256 + threadIdx.x;
    int kidx = idx >> 5, j = idx & 31;
    int slot = kidx >> 7, p = kidx & 127;
    int col = (p & 7) * 16 + (p >> 3);
    WmT[j * 256 + kidx] = f2h(Wm[(slot * 128 + col) * 32 + j]);
  }
}

// K1: FUSED projection GEMM + edge histogram. Blocks 0..1562: proj (proven
// round-6 shape, 4 waves x 16 rows). Blocks 1563..: hist (independent root:
// reads only dst, atomics on cnt, writes rank). Overlapping hides hist's
// atomic latency under proj's MFMA/memory work.
__global__ __launch_bounds__(256, 4) void k_projhist(const float* __restrict__ feat,
    const unsigned short* __restrict__ Btg,
    unsigned short* __restrict__ ftg,
    float* __restrict__ elg, float* __restrict__ erg,
    const int* __restrict__ dst, int* __restrict__ cnt, int* __restrict__ rank)
{
  if (blockIdx.x >= NPROJB) {                              // ---- hist part ----
    int idx = (blockIdx.x - NPROJB) * 256 + threadIdx.x;
    if (idx >= TE) return;
    int t = idx / N_EDGES;
    int d = dst[idx];
    bool keep = (t < 2) ? (d < N_A) : (d >= N_A);
    if (keep) rank[idx] = atomicAdd(&cnt[t * N_NODES + d], 1);
    return;
  }
  // ---- proj part ----
  __shared__ __align__(16) unsigned short Bs[TILE_E];      // 36.8 KB -> 4 blocks/CU
  const int tid = threadIdx.x;
  const int wave = tid >> 6, lane = tid & 63;
  const int l15 = lane & 15, g = lane >> 4;
  const int wrow0 = blockIdx.x * 64 + wave * 16;

  short8 a[4];
  {
    int row = wrow0 + l15;
    const float* fr = feat + (size_t)(row < N_NODES ? row : N_NODES - 1) * D_IN;
#pragma unroll
    for (int kt = 0; kt < 4; ++kt) {
      float4 v0 = *(const float4*)(fr + kt * 32 + g * 8);
      float4 v1 = *(const float4*)(fr + kt * 32 + g * 8 + 4);
      short8 s;
      s[0] = (short)f2b(v0.x); s[1] = (short)f2b(v0.y);
      s[2] = (short)f2b(v0.z); s[3] = (short)f2b(v0.w);
      s[4] = (short)f2b(v1.x); s[5] = (short)f2b(v1.y);
      s[6] = (short)f2b(v1.z); s[7] = (short)f2b(v1.w);
      a[kt] = s;
    }
  }

  for (int t = 0; t < N_T; ++t) {
    if (t > 0) __syncthreads();
    {
      const uint4* src = (const uint4*)(Btg + (size_t)t * TILE_E);
      uint4* dstv = (uint4*)Bs;
#pragma unroll
      for (int i = 0; i < 9; ++i)
        dstv[i * 256 + tid] = src[i * 256 + tid];
    }
    __syncthreads();

    f32x4 acc[8];
#pragma unroll
    for (int ct = 0; ct < 8; ++ct) {
      f32x4 c = {0.f, 0.f, 0.f, 0.f};
#pragma unroll
      for (int kt = 0; kt < 4; ++kt) {
        int row = ct * 16 + l15;
        int boff = (row * 256 + kt * 64 + g * 16) ^ ((l15 & 7) << 4);
        short8 b = *(const short8*)((const char*)Bs + boff);
        c = __builtin_amdgcn_mfma_f32_16x16x32_bf16(a[kt], b, c, 0, 0, 0);
      }
      acc[ct] = c;
    }
    {
      f32x4 c8 = {0.f, 0.f, 0.f, 0.f};
#pragma unroll
      for (int kt = 0; kt < 4; ++kt) {
        int row = 128 + l15;
        int boff = (row * 256 + kt * 64 + g * 16) ^ ((l15 & 7) << 4);
        short8 b = *(const short8*)((const char*)Bs + boff);
        c8 = __builtin_amdgcn_mfma_f32_16x16x32_bf16(a[kt], b, c8, 0, 0, 0);
      }
      if (l15 < 8) {
#pragma unroll
        for (int r = 0; r < 4; ++r) {
          int row = wrow0 + g * 4 + r;
          if (row < N_NODES) {
            float v = c8[r];
            if (l15 < 4) elg[((size_t)t * N_NODES + row) * 4 + l15] = v;
            else         erg[((size_t)t * N_NODES + row) * 4 + (l15 - 4)] = v;
          }
        }
      }
    }
    // direct permuted ft store (F16): row-position p = l15*8 + ct
#pragma unroll
    for (int r = 0; r < 4; ++r) {
      int row = wrow0 + g * 4 + r;
      if (row < N_NODES) {
        uint4 o;
        o.x = pkh(acc[0][r], acc[1][r]);
        o.y = pkh(acc[2][r], acc[3][r]);
        o.z = pkh(acc[4][r], acc[5][r]);
        o.w = pkh(acc[6][r], acc[7][r]);
        *(uint4*)(ftg + ((size_t)t * N_NODES + row) * HF + l15 * 8) = o;
      }
    }
  }
}

__global__ __launch_bounds__(256) void k_scan1(const int* __restrict__ cnt,
    int* __restrict__ ofs, int* __restrict__ bsum) {
  __shared__ int ts[256];
  int b = blockIdx.x, t = threadIdx.x;
  int base = b * 1024 + t * 4;
  int v0 = 0, v1 = 0, v2 = 0, v3 = 0;
  if (base + 0 < TN) v0 = cnt[base + 0];
  if (base + 1 < TN) v1 = cnt[base + 1];
  if (base + 2 < TN) v2 = cnt[base + 2];
  if (base + 3 < TN) v3 = cnt[base + 3];
  int s = v0 + v1 + v2 + v3;
  ts[t] = s;
  __syncthreads();
  for (int o = 1; o < 256; o <<= 1) {
    int x = (t >= o) ? ts[t - o] : 0;
    __syncthreads();
    ts[t] += x;
    __syncthreads();
  }
  int run = ts[t] - s;
  if (base + 0 < TN) ofs[base + 0] = run; run += v0;
  if (base + 1 < TN) ofs[base + 1] = run; run += v1;
  if (base + 2 < TN) ofs[base + 2] = run; run += v2;
  if (base + 3 < TN) ofs[base + 3] = run;
  if (t == 255) bsum[b] = ts[255];
}

__global__ __launch_bounds__(512) void k_scan2(int* __restrict__ bsum) {
  __shared__ int ts[512];
  int t = threadIdx.x;
  int v = (t < NB1) ? bsum[t] : 0;
  ts[t] = v;
  __syncthreads();
  for (int o = 1; o < 512; o <<= 1) {
    int x = (t >= o) ? ts[t - o] : 0;
    __syncthreads();
    ts[t] += x;
    __syncthreads();
  }
  if (t < NB1) bsum[t] = ts[t] - v;
}

// K3: slim scatter: 4 B record = src ft-row index; position from ofs+bsum+rank.
__global__ __launch_bounds__(256) void k_scatter(const int* __restrict__ src, const int* __restrict__ dst,
    const int* __restrict__ ofs, const int* __restrict__ bsum, const int* __restrict__ rank,
    int* __restrict__ bkt) {
  int idx = blockIdx.x * 256 + threadIdx.x;
  if (idx >= TE) return;
  int t = idx / N_EDGES;
  int d = dst[idx];
  bool keep = (t < 2) ? (d < N_A) : (d >= N_A);
  if (!keep) return;
  int key = t * N_NODES + d;
  int p = ofs[key] + bsum[key >> 10] + rank[idx];
  bkt[p] = t * N_NODES + src[idx];
}

// K4: gather. 8 pairs/wave, 8 lanes/pair, MASKED UNROLL-4: 16 loads in
// flight per iteration (4 records + 4 el + 8 ft rows); invalid edges clamp
// to index i (valid) with weight forced to 0. f16 __hfma2 accumulation.
__global__ __launch_bounds__(256) void k_gather(const int* __restrict__ bkt,
    const int* __restrict__ ofs, const int* __restrict__ cnt, const int* __restrict__ bsum,
    const float* __restrict__ elg, const float* __restrict__ erg,
    const uint4* __restrict__ ftu, uint4* __restrict__ aggb)
{
  int wid = blockIdx.x * 4 + (threadIdx.x >> 6);
  int lane = threadIdx.x & 63;
  int g8 = lane >> 3, l7 = lane & 7;
  int pid = wid * 8 + g8;                      // pair id = node*2 + slot
  int n = pid >> 1, slot = pid & 1;
  int t = slot + ((n >= N_A) ? 2 : 0);
  int key = t * N_NODES + n;
  int base = ofs[key] + bsum[key >> 10];
  int c = cnt[key];
  float4 er4 = *(const float4*)(erg + (size_t)key * 4);
  __half2 A0 = __float2half2_rn(0.f), A1 = A0, A2 = A0, A3 = A0;
  __half2 B0 = A0, B1 = A0, B2 = A0, B3 = A0;
  float d0 = 0.f, d1 = 0.f, d2 = 0.f, d3 = 0.f;
  int qb = l7 * 2;
  for (int i = 0; i < c; i += 4) {
    bool v1 = i + 1 < c, v2 = i + 2 < c, v3 = i + 3 < c;
    int e0 = base + i;
    int e1 = base + (v1 ? i + 1 : i);
    int e2 = base + (v2 ? i + 2 : i);
    int e3 = base + (v3 ? i + 3 : i);
    int s0 = bkt[e0], s1 = bkt[e1], s2 = bkt[e2], s3 = bkt[e3];
    float4 eA = *(const float4*)(elg + (size_t)s0 * 4);
    float4 eB = *(const float4*)(elg + (size_t)s1 * 4);
    float4 eC = *(const float4*)(elg + (size_t)s2 * 4);
    float4 eD = *(const float4*)(elg + (size_t)s3 * 4);
    uint4 u0a = ftu[(size_t)s0 * 16 + qb], u0b = ftu[(size_t)s0 * 16 + qb + 1];
    uint4 u1a = ftu[(size_t)s1 * 16 + qb], u1b = ftu[(size_t)s1 * 16 + qb + 1];
    uint4 u2a = ftu[(size_t)s2 * 16 + qb], u2b = ftu[(size_t)s2 * 16 + qb + 1];
    uint4 u3a = ftu[(size_t)s3 * 16 + qb], u3b = ftu[(size_t)s3 * 16 + qb + 1];
    float s;
    float wa0, wa1, wa2, wa3, wb0, wb1, wb2, wb3;
    float wc0, wc1, wc2, wc3, wd0, wd1, wd2, wd3;
    s = eA.x + er4.x; wa0 = exp2f(fmaxf(s, 0.2f * s));
    s = eA.y + er4.y; wa1 = exp2f(fmaxf(s, 0.2f * s));
    s = eA.z + er4.z; wa2 = exp2f(fmaxf(s, 0.2f * s));
    s = eA.w + er4.w; wa3 = exp2f(fmaxf(s, 0.2f * s));
    s = eB.x + er4.x; wb0 = exp2f(fmaxf(s, 0.2f * s));
    s = eB.y + er4.y; wb1 = exp2f(fmaxf(s, 0.2f * s));
    s = eB.z + er4.z; wb2 = exp2f(fmaxf(s, 0.2f * s));
    s = eB.w + er4.w; wb3 = exp2f(fmaxf(s, 0.2f * s));
    s = eC.x + er4.x; wc0 = exp2f(fmaxf(s, 0.2f * s));
    s = eC.y + er4.y; wc1 = exp2f(fmaxf(s, 0.2f * s));
    s = eC.z + er4.z; wc2 = exp2f(fmaxf(s, 0.2f * s));
    s = eC.w + er4.w; wc3 = exp2f(fmaxf(s, 0.2f * s));
    s = eD.x + er4.x; wd0 = exp2f(fmaxf(s, 0.2f * s));
    s = eD.y + er4.y; wd1 = exp2f(fmaxf(s, 0.2f * s));
    s = eD.z + er4.z; wd2 = exp2f(fmaxf(s, 0.2f * s));
    s = eD.w + er4.w; wd3 = exp2f(fmaxf(s, 0.2f * s));
    if (!v1) { wb0 = wb1 = wb2 = wb3 = 0.f; }
    if (!v2) { wc0 = wc1 = wc2 = wc3 = 0.f; }
    if (!v3) { wd0 = wd1 = wd2 = wd3 = 0.f; }
    d0 += wa0 + wb0 + wc0 + wd0;
    d1 += wa1 + wb1 + wc1 + wd1;
    d2 += wa2 + wb2 + wc2 + wd2;
    d3 += wa3 + wb3 + wc3 + wd3;
    __half2 h0, h1, h2, h3;
    h0 = __float2half2_rn(wa0); h1 = __float2half2_rn(wa1);
    h2 = __float2half2_rn(wa2); h3 = __float2half2_rn(wa3);
    A0 = __hfma2(w2h(u0a.x), h0, A0); A1 = __hfma2(w2h(u0a.y), h1, A1);
    A2 = __hfma2(w2h(u0a.z), h2, A2); A3 = __hfma2(w2h(u0a.w), h3, A3);
    B0 = __hfma2(w2h(u0b.x), h0, B0); B1 = __hfma2(w2h(u0b.y), h1, B1);
    B2 = __hfma2(w2h(u0b.z), h2, B2); B3 = __hfma2(w2h(u0b.w), h3, B3);
    h0 = __float2half2_rn(wb0); h1 = __float2half2_rn(wb1);
    h2 = __float2half2_rn(wb2); h3 = __float2half2_rn(wb3);
    A0 = __hfma2(w2h(u1a.x), h0, A0); A1 = __hfma2(w2h(u1a.y), h1, A1);
    A2 = __hfma2(w2h(u1a.z), h2, A2); A3 = __hfma2(w2h(u1a.w), h3, A3);
    B0 = __hfma2(w2h(u1b.x), h0, B0); B1 = __hfma2(w2h(u1b.y), h1, B1);
    B2 = __hfma2(w2h(u1b.z), h2, B2); B3 = __hfma2(w2h(u1b.w), h3, B3);
    h0 = __float2half2_rn(wc0); h1 = __float2half2_rn(wc1);
    h2 = __float2half2_rn(wc2); h3 = __float2half2_rn(wc3);
    A0 = __hfma2(w2h(u2a.x), h0, A0); A1 = __hfma2(w2h(u2a.y), h1, A1);
    A2 = __hfma2(w2h(u2a.z), h2, A2); A3 = __hfma2(w2h(u2a.w), h3, A3);
    B0 = __hfma2(w2h(u2b.x), h0, B0); B1 = __hfma2(w2h(u2b.y), h1, B1);
    B2 = __hfma2(w2h(u2b.z), h2, B2); B3 = __hfma2(w2h(u2b.w), h3, B3);
    h0 = __float2half2_rn(wd0); h1 = __float2half2_rn(wd1);
    h2 = __float2half2_rn(wd2); h3 = __float2half2_rn(wd3);
    A0 = __hfma2(w2h(u3a.x), h0, A0); A1 = __hfma2(w2h(u3a.y), h1, A1);
    A2 = __hfma2(w2h(u3a.z), h2, A2); A3 = __hfma2(w2h(u3a.w), h3, A3);
    B0 = __hfma2(w2h(u3b.x), h0, B0); B1 = __hfma2(w2h(u3b.y), h1, B1);
    B2 = __hfma2(w2h(u3b.z), h2, B2); B3 = __hfma2(w2h(u3b.w), h3, B3);
  }
  __half2 i0 = __float2half2_rn((c > 0) ? 1.f / d0 : 0.f);
  __half2 i1 = __float2half2_rn((c > 0) ? 1.f / d1 : 0.f);
  __half2 i2 = __float2half2_rn((c > 0) ? 1.f / d2 : 0.f);
  __half2 i3 = __float2half2_rn((c > 0) ? 1.f / d3 : 0.f);
  uint4 oA, oB;
  oA.x = h2w(__hmul2(A0, i0)); oA.y = h2w(__hmul2(A1, i1));
  oA.z = h2w(__hmul2(A2, i2)); oA.w = h2w(__hmul2(A3, i3));
  oB.x = h2w(__hmul2(B0, i0)); oB.y = h2w(__hmul2(B1, i1));
  oB.z = h2w(__hmul2(B2, i2)); oB.w = h2w(__hmul2(B3, i3));
  size_t ob = (size_t)n * 32 + slot * 16 + qb;
  aggb[ob] = oA;
  aggb[ob + 1] = oB;
}

// K5: merge GEMM via F16 MFMA. 64 nodes/block, out = agg(f16, permuted-k) @ WmT + bm.
__global__ __launch_bounds__(256) void k_merge(const unsigned short* __restrict__ aggb,
    const unsigned short* __restrict__ WmT, const float* __restrict__ bm,
    float* __restrict__ out)
{
  __shared__ __align__(16) unsigned short Al[64 * 264];
  __shared__ __align__(16) unsigned short Bl[32 * 264];
  int n0 = blockIdx.x * 64;
  int tid = threadIdx.x;
  const uint4* asrc = (const uint4*)(aggb + (size_t)n0 * 256);
  for (int i = tid; i < 2048; i += 256) {
    int r = i >> 5, c = i & 31;
    *(uint4*)&Al[r * 264 + c * 8] = asrc[r * 32 + c];
  }
  for (int i = tid; i < 1024; i += 256) {
    int r = i >> 5, c = i & 31;
    *(uint4*)&Bl[r * 264 + c * 8] = ((const uint4*)WmT)[r * 32 + c];
  }
  __syncthreads();
  int wave = tid >> 6, lane = tid & 63;
  int l15 = lane & 15, lk = (lane >> 4) * 8;
  half8 a[8];
#pragma unroll
  for (int kt = 0; kt < 8; ++kt)
    a[kt] = *(const half8*)&Al[(wave * 16 + l15) * 264 + kt * 32 + lk];
  f32x4 acc0 = {0.f, 0.f, 0.f, 0.f}, acc1 = {0.f, 0.f, 0.f, 0.f};
#pragma unroll
  for (int kt = 0; kt < 8; ++kt) {
    half8 b0 = *(const half8*)&Bl[l15 * 264 + kt * 32 + lk];
    half8 b1 = *(const half8*)&Bl[(16 + l15) * 264 + kt * 32 + lk];
    acc0 = __builtin_amdgcn_mfma_f32_16x16x32_f16(a[kt], b0, acc0, 0, 0, 0);
    acc1 = __builtin_amdgcn_mfma_f32_16x16x32_f16(a[kt], b1, acc1, 0, 0, 0);
  }
  float bm0 = bm[l15], bm1 = bm[16 + l15];
#pragma unroll
  for (int r = 0; r < 4; ++r) {
    int row = n0 + wave * 16 + (lane >> 4) * 4 + r;
    if (row < N_NODES) {
      out[(size_t)row * 32 + l15] = acc0[r] + bm0;
      out[(size_t)row * 32 + 16 + l15] = acc1[r] + bm1;
    }
  }
}

extern "C" void kernel_launch(void* const* d_in, const int* in_sizes, int n_in,
                              void* d_out, int out_size, void* d_ws, size_t ws_size,
                              hipStream_t stream)
{
  const float* feat = (const float*)d_in[0];
  const int*   src  = (const int*)d_in[1];
  const int*   dst  = (const int*)d_in[2];
  const float* W    = (const float*)d_in[4];
  const float* al   = (const float*)d_in[5];
  const float* ar   = (const float*)d_in[6];
  const float* Wm   = (const float*)d_in[7];
  const float* bm   = (const float*)d_in[8];
  float* out = (float*)d_out;
  (void)in_sizes; (void)n_in; (void)out_size; (void)ws_size;

  char* w = (char*)d_ws;
  size_t o = 0;
  auto take = [&](size_t bytes) -> void* {
    void* p = w + o;
    o += (bytes + 255) & ~(size_t)255;
    return p;
  };
  unsigned short* Btg = (unsigned short*)take((size_t)N_T * TILE_E * 2);         // 147 KB
  unsigned short* WmT = (unsigned short*)take((size_t)32 * 256 * 2);             // 16 KB
  unsigned short* ftg = (unsigned short*)take((size_t)N_T * N_NODES * HF * 2);   // 102.4 MB
  float* elg   = (float*)take((size_t)N_T * N_NODES * 4 * 4);                    // 6.4 MB
  float* erg   = (float*)take((size_t)N_T * N_NODES * 4 * 4);                    // 6.4 MB
  int*   cntb  = (int*)take((size_t)TN * 4);                                     // 1.6 MB
  int*   ofs   = (int*)take((size_t)TN * 4);
  int*   bsum  = (int*)take(4096);
  int*   rank  = (int*)take((size_t)TE * 4);                                     // 8 MB
  int*   bkt   = (int*)take((size_t)TE * 4);                                     // 8 MB
  unsigned short* aggb = (unsigned short*)take((size_t)(N_NODES + 64) * 256 * 2);// 51.2 MB

  hipMemsetAsync(cntb, 0, (size_t)TN * 4, stream);

  k_prep<<<34, 256, 0, stream>>>(W, al, ar, Wm, Btg, WmT);
  k_projhist<<<NPROJB + NHISTB, 256, 0, stream>>>(feat, Btg, ftg, elg, erg, dst, cntb, rank);
  k_scan1<<<NB1, 256, 0, stream>>>(cntb, ofs, bsum);
  k_scan2<<<1, 512, 0, stream>>>(bsum);
  k_scatter<<<(TE + 255) / 256, 256, 0, stream>>>(src, dst, ofs, bsum, rank, bkt);
  k_gather<<<6250, 256, 0, stream>>>(bkt, ofs, cntb, bsum, elg, erg, (const uint4*)ftg, (uint4*)aggb);
  k_merge<<<1563, 256, 0, stream>>>(aggb, WmT, bm, out);
}